// Round 3
// baseline (284.083 us; speedup 1.0000x reference)
//
#include <hip/hip_runtime.h>

// LSTM_67980742362036: 2-layer LSTM (B=4096, T=200, I=32, H=6) + linear head.
// R11 = 2 chains per wave (2048 blocks x 64 threads, each wave = 2 batches).
// Rationale: exactly 4 batch-chains exist per SIMD (4096/1024, fixed). R8
// packaged them as 4 waves x 1 chain: zero in-wave ILP, VALUBusy 72%, and
// R10 proved the stall is not removable by shrinking one wave's instruction
// stream. Here each wave interleaves TWO independent chains step-by-step, so
// chain stalls are filled in-wave; the second wave on the SIMD covers bursts.
//  - Projection: compact per-window bursts (R10's verified PROJW) into two
//    64-slot LDS rings; ~14 instr/batch-step amortized vs spread's ~35.
//  - Scan: rolled groups of 8 steps (ds_read offset = compile-time imm within
//    group; ring base VGPR advanced per group with wrap at slot 64).
//  - Shared WA/WB/base1 across the two chains (same weights).
//  - Single wave per block: in-wave LDS ordering, zero barriers.
//  - VGPR budget 256 at 2 waves/SIMD -> R9's regalloc collapse can't recur.
// Numerics: per-batch op order identical to verified R9/R10 -> absmax 0.

#define TLEN  200
#define ISZ   32
#define HSZ   6
#define RPITCH 25
#define WPITCH 36                      // W row pitch in dwords (bank-split fix)
#define RB0   0                        // ring for batch 0: 64 x 25
#define RB1   1600                     // ring for batch 1
#define WOFF  3200                     // Wih0: 24 rows x WPITCH
#define BOFF  (WOFF + 24 * WPITCH)     // folded bias: 24      (= 4064)
#define LDS_DW (BOFF + 24)             // 4088 dwords = 16352 B

__device__ __forceinline__ float fast_sig(float x) {
    return __builtin_amdgcn_rcpf(1.0f + __expf(-x));   // ~1e-7 vs 3.7e-3 thr
}
__device__ __forceinline__ float rl(float v, int l) {
    return __int_as_float(__builtin_amdgcn_readlane(__float_as_int(v), l));
}
template <int CTRL>
__device__ __forceinline__ float qperm(float v) {
    return __int_as_float(__builtin_amdgcn_mov_dpp(__float_as_int(v), CTRL, 0xf, 0xf, true));
}
__device__ __forceinline__ float dot4(float4 w, float4 v) {
    return fmaf(w.x, v.x, fmaf(w.y, v.y, fmaf(w.z, v.z, w.w * v.w)));
}

__global__ __launch_bounds__(64) void lstm_two(
    const float* __restrict__ x,
    const float* __restrict__ Wih0, const float* __restrict__ Whh0,
    const float* __restrict__ bih0, const float* __restrict__ bhh0,
    const float* __restrict__ Wih1, const float* __restrict__ Whh1,
    const float* __restrict__ bih1, const float* __restrict__ bhh1,
    const float* __restrict__ Wlin, const float* __restrict__ blin,
    float* __restrict__ out)
{
    __shared__ float lds[LDS_DW];

    const int lane = threadIdx.x;
    const int b0   = blockIdx.x << 1;
    const float* xb0 = x + (size_t)b0 * TLEN * ISZ;
    const float* xb1 = xb0 + TLEN * ISZ;

    // projection roles: pair (2L,2L+1) owns timestep base+L; o selects 12 rows
    const int o = lane & 1;
    const int L = lane >> 1;

    // scan roles: lane = half*32 + 4*unit + gate(i,f,g,o)
    const bool loHalf = (lane < 32);
    const int  p  = lane & 3;
    const int  jq = (lane & 31) >> 2;
    const int  j  = (jq < HSZ) ? jq : 0;
    const int  r  = 6 * p + j;

#define LDSW(ROW, KCQ) (*(const float4*)&lds[WOFF + (o * 12 + (ROW)) * WPITCH + ((KCQ) << 2)])

    // ---- stage Wih0 + folded bias (single wave: in-wave ordering) ----
#pragma unroll
    for (int k = 0; k < 13; ++k) {
        const int idx = lane + (k << 6);
        if (idx < 768) {
            const int row = idx >> 5, kk = idx & 31;
            lds[WOFF + row * WPITCH + kk] = Wih0[idx];
        } else if (idx < 792) {
            lds[BOFF + idx - 768] = bih0[idx - 768] + bhh0[idx - 768];
        }
    }

    // ---- scan weights (g-gate x2 pre-fold), shared by both chains ----
    float WA[6], WB[6], base1 = 0.0f, sgc = 1.0f, tgc = 0.0f;
#pragma unroll
    for (int k = 0; k < 6; ++k) { WA[k] = 0.0f; WB[k] = 0.0f; }
    if (loHalf) {
#pragma unroll
        for (int k = 0; k < 6; ++k) WA[k] = Whh0[r * 6 + k];
    } else {
#pragma unroll
        for (int k = 0; k < 6; ++k) { WA[k] = Wih1[r * 6 + k]; WB[k] = Whh1[r * 6 + k]; }
        base1 = bih1[r] + bhh1[r];
    }
    if (p == 2) {   // cell gate: tanh(g) = 2*sig(2g)-1; fold the 2g into weights
#pragma unroll
        for (int k = 0; k < 6; ++k) { WA[k] *= 2.0f; WB[k] *= 2.0f; }
        base1 *= 2.0f; sgc = 2.0f; tgc = -1.0f;
    }

    // ---- compact projection of one window (R10-verified op order) ----
    auto proj1 = [&](const float* xb, int rb, int wp) {
        const int t = (wp << 5) + L;
        const float4* xr4 = (const float4*)(xb + (size_t)min(t, TLEN - 1) * ISZ);
        float a0c[12];
#pragma unroll
        for (int jj = 0; jj < 12; ++jj) a0c[jj] = 0.0f;
#pragma unroll
        for (int hh = 0; hh < 2; ++hh) {               // x in 2 half-bursts
            float4 xw[4];
#pragma unroll
            for (int q = 0; q < 4; ++q) xw[q] = xr4[(hh << 2) + q];
#pragma unroll
            for (int jh = 0; jh < 2; ++jh)
#pragma unroll
                for (int kc = 0; kc < 4; ++kc)
#pragma unroll
                    for (int jj = jh * 6; jj < jh * 6 + 6; ++jj)
                        a0c[jj] += dot4(LDSW(jj, (hh << 2) + kc), xw[kc]);
        }
        const int slot = t & 63;
#pragma unroll
        for (int jj = 0; jj < 12; ++jj) {
            float v = a0c[jj] + lds[BOFF + o * 12 + jj];
            if (jj < 6) v = (o == 1) ? v * 2.0f : v;   // g-rows 12..17 pre-x2
            lds[rb + slot * RPITCH + o * 12 + jj] = v;
        }
    };

    proj1(xb0, RB0, 0); proj1(xb1, RB1, 0);
    proj1(xb0, RB0, 1); proj1(xb1, RB1, 1);

    // ---- scan state ----
    int gd  = 0;                       // group base (dwords into ring), multiple of 200
    int av0 = RB0 + r, av1 = RB1 + r;  // per-chain ds addr bases (dword index)
    float c0 = 0.0f, h0 = 0.0f, c1 = 0.0f, h1 = 0.0f;
    float xp0 = lds[av0], xp1 = lds[av1];   // xp(0)

#define SSTEP(Hv, Cv, XPv, XNv) do { \
    const float h10 = rl(Hv, 0),  h11 = rl(Hv, 4),  h12 = rl(Hv, 8); \
    const float h13 = rl(Hv, 12), h14 = rl(Hv, 16), h15 = rl(Hv, 20); \
    const float h20 = rl(Hv, 32), h21 = rl(Hv, 36), h22 = rl(Hv, 40); \
    const float h23 = rl(Hv, 44), h24 = rl(Hv, 48), h25 = rl(Hv, 52); \
    const float _g0 = loHalf ? (XPv) : base1; \
    const float _a0 = fmaf(WA[0], h10, fmaf(WA[2], h12, fmaf(WA[4], h14, _g0))); \
    const float _a1 = fmaf(WA[1], h11, fmaf(WA[3], h13, WA[5] * h15)); \
    const float _b0 = fmaf(WB[0], h20, fmaf(WB[2], h22, WB[4] * h24)); \
    const float _b1 = fmaf(WB[1], h21, fmaf(WB[3], h23, WB[5] * h25)); \
    const float _g  = (_a0 + _a1) + (_b0 + _b1); \
    const float _aG = fmaf(sgc, fast_sig(_g), tgc); \
    const float _iq = qperm<0x00>(_aG), _fq = qperm<0x55>(_aG); \
    const float _gq = qperm<0xAA>(_aG), _oq = qperm<0xFF>(_aG); \
    Cv = fmaf(_fq, Cv, _iq * _gq); \
    const float _th = fmaf(2.0f, fast_sig(2.0f * Cv), -1.0f); \
    Hv = _oq * _th; \
    XPv = (XNv); \
} while (0)

#define PAIR(SL) do { \
    const float _xn0 = lds[av0 + (SL)]; \
    const float _xn1 = lds[av1 + (SL)]; \
    SSTEP(h0, c0, xp0, _xn0); \
    SSTEP(h1, c1, xp1, _xn1); \
} while (0)

#define PAIR_NP() do { \
    SSTEP(h0, c0, xp0, xp0); \
    SSTEP(h1, c1, xp1, xp1); \
} while (0)

#define ADV() do { \
    const int _adv = (gd == 1400) ? -1400 : 200; \
    gd += _adv; av0 += _adv; av1 += _adv; \
} while (0)

#define PEEL(Hv, Cv, XPv) do { \
    const float _pg  = loHalf ? (XPv) : base1; \
    const float _paG = fmaf(sgc, fast_sig(_pg), tgc); \
    const float _piq = qperm<0x00>(_paG), _pgq = qperm<0xAA>(_paG), _poq = qperm<0xFF>(_paG); \
    const float _pcn = _piq * _pgq; \
    const float _pth = fmaf(2.0f, fast_sig(2.0f * _pcn), -1.0f); \
    Cv = loHalf ? _pcn : 0.0f; \
    Hv = loHalf ? (_poq * _pth) : 0.0f; \
} while (0)

    // ---- it = 0 peel (no h-dependency; L1 phantom stays 0) ----
    PEEL(h0, c0, xp0);
    PEEL(h1, c1, xp1);
    xp0 = lds[av0 + RPITCH];           // xp(1)
    xp1 = lds[av1 + RPITCH];

    // ---- group 0: it = 1..7 ----
    PAIR(50); PAIR(75); PAIR(100); PAIR(125); PAIR(150); PAIR(175);
    ADV(); PAIR(0);

    // ---- groups m = 1..24: it = 8..199; PROJ(w+1) at each window top ----
#pragma unroll 1
    for (int m = 1; m <= 24; ++m) {
        if ((m & 3) == 0) {
            const int wp = (m >> 2) + 1;           // window being produced
            if (wp <= 6) { proj1(xb0, RB0, wp); proj1(xb1, RB1, wp); }
        }
        PAIR(25); PAIR(50); PAIR(75); PAIR(100); PAIR(125); PAIR(150); PAIR(175);
        ADV(); PAIR(0);
    }

    // ---- it = 200 (lo-half xp stale: finite, unused) + output ----
    PAIR_NP();
    {
        float s0 = blin[0], s1 = blin[0];
#pragma unroll
        for (int k = 0; k < 6; ++k) {
            s0 = fmaf(Wlin[k], rl(h0, 32 + 4 * k), s0);
            s1 = fmaf(Wlin[k], rl(h1, 32 + 4 * k), s1);
        }
        if (lane == 0) { out[b0] = s0; out[b0 + 1] = s1; }
    }

#undef LDSW
#undef SSTEP
#undef PAIR
#undef PAIR_NP
#undef ADV
#undef PEEL
}

extern "C" void kernel_launch(void* const* d_in, const int* in_sizes, int n_in,
                              void* d_out, int out_size, void* d_ws, size_t ws_size,
                              hipStream_t stream) {
    const float* x    = (const float*)d_in[0];
    const float* Wih0 = (const float*)d_in[1];
    const float* Whh0 = (const float*)d_in[2];
    const float* bih0 = (const float*)d_in[3];
    const float* bhh0 = (const float*)d_in[4];
    const float* Wih1 = (const float*)d_in[5];
    const float* Whh1 = (const float*)d_in[6];
    const float* bih1 = (const float*)d_in[7];
    const float* bhh1 = (const float*)d_in[8];
    const float* Wlin = (const float*)d_in[9];
    const float* blin = (const float*)d_in[10];
    float* out = (float*)d_out;

    lstm_two<<<2048, 64, 0, stream>>>(x, Wih0, Whh0, bih0, bhh0,
                                      Wih1, Whh1, bih1, bhh1,
                                      Wlin, blin, out);
}

// Round 4
// 253.166 us; speedup vs baseline: 1.1221x; 1.1221x over previous
//
#include <hip/hip_runtime.h>

// LSTM_67980742362036: 2-layer LSTM (B=4096, T=200, I=32, H=6) + linear head.
// R12 = lane-per-unit scan. Model fit across R8/R10/R11: wall = 200 x (per-wave
// per-step serial latency ~1450-1600cy); issue is spare (R10: -40% VALU, same
// wall); the latency is interleavable (R11: 2 temporal chains -> 1020cy/chain).
// So: collapse the per-step structure. 16-lane group = 1 batch:
//   role 0-5 : L0 unit u — ALL 4 gates + c,h in-lane (no DPP, no readlane)
//   role 6-11: L1 unit u — skewed 1 step (R8 phantom scheme), bias via xq ptr
//   role12-15: idle dummies
// Cross-lane = 12 ds_swizzle group-broadcasts/step (h0[0..5], h1[0..5]).
// xp projection = separate kernel (R10-proven math) writing float4[t][unit],
// so scan's per-step memory = ONE 16B global load (4-deep pipeline); L1 lanes'
// load ptr -> constant bias cell (stride 0) => fully uniform step code.
// Scan kernel: 1024 blocks x 64, NO LDS, NO barriers.
// Fallback: proven R8 kernel if ws_size too small.

#define TLEN  200
#define ISZ   32
#define HSZ   6
#define WPITCH 36                      // W row pitch in dwords (bank-split fix)

// ---- proj kernel LDS ----
#define PWOFF 0
#define PBOFF (24 * WPITCH)            // 864
#define PLDS_DW (PBOFF + 24)           // 888 dwords

// ---- fallback (R8) LDS layout ----
#define RPITCH 25
#define RING_DW (64 * RPITCH)
#define FWOFF  RING_DW
#define FBOFF  (FWOFF + 24 * WPITCH)
#define FLDS_DW (FBOFF + 24)           // 9952 B

#define XP4_COUNT ((size_t)4096 * TLEN * 6)          // float4 elements
#define WS_REQ    ((XP4_COUNT + 6) * 16)             // + bias4 table

__device__ __forceinline__ float fast_sig(float x) {
    return __builtin_amdgcn_rcpf(1.0f + __expf(-x));
}
__device__ __forceinline__ float tanh_s(float x) {     // tanh via 2*sig(2x)-1
    return fmaf(2.0f, fast_sig(x + x), -1.0f);
}
__device__ __forceinline__ float rl(float v, int l) {
    return __int_as_float(__builtin_amdgcn_readlane(__float_as_int(v), l));
}
template <int CTRL>
__device__ __forceinline__ float qperm(float v) {
    return __int_as_float(__builtin_amdgcn_mov_dpp(__float_as_int(v), CTRL, 0xf, 0xf, true));
}
template <int OFF>
__device__ __forceinline__ float swz(float v) {        // BitMode group-broadcast
    return __int_as_float(__builtin_amdgcn_ds_swizzle(__float_as_int(v), OFF));
}
__device__ __forceinline__ float dot4(float4 w, float4 v) {
    return fmaf(w.x, v.x, fmaf(w.y, v.y, fmaf(w.z, v.z, w.w * v.w)));
}

// ======================= kernel 1: projection (R10 math, transposed store) =======================
__global__ __launch_bounds__(64) void proj_k(
    const float* __restrict__ x,    const float* __restrict__ Wih0,
    const float* __restrict__ bih0, const float* __restrict__ bhh0,
    const float* __restrict__ bih1, const float* __restrict__ bhh1,
    float4* __restrict__ xp4)       // [b*200+t][u]; bias4 table at XP4_COUNT
{
    __shared__ float lds[PLDS_DW];
    const int lane = threadIdx.x;
    const int b    = blockIdx.x;
    const int o = lane & 1;            // unit-half now: o=0 -> units 0-2, o=1 -> 3-5
    const int L = lane >> 1;
    const float* xb = x + (size_t)b * TLEN * ISZ;

    // stage Wih0 + bias, PERMUTED: global row r -> slot (r%6)/3*12 + (r/6)*3 + (r%3)
#pragma unroll
    for (int k = 0; k < 13; ++k) {
        const int idx = lane + (k << 6);
        if (idx < 768) {
            const int row = idx >> 5, kk = idx & 31;
            const int slot = ((row % 6) / 3) * 12 + (row / 6) * 3 + (row % 3);
            lds[PWOFF + slot * WPITCH + kk] = Wih0[idx];
        } else if (idx < 792) {
            const int r = idx - 768;
            const int slot = ((r % 6) / 3) * 12 + (r / 6) * 3 + (r % 3);
            lds[PBOFF + slot] = bih0[r] + bhh0[r];
        }
    }
    // bias4 table for layer-1 lanes: bias4[u][gate] = bih1[g*6+u]+bhh1[g*6+u]
    if (blockIdx.x == 0 && lane < 24) {
        const int u = lane % 6, g = lane / 6;
        ((float*)(xp4 + XP4_COUNT))[u * 4 + g] = bih1[g * 6 + u] + bhh1[g * 6 + u];
    }

#define PLDSW(ROW, KCQ) (*(const float4*)&lds[PWOFF + (o * 12 + (ROW)) * WPITCH + ((KCQ) << 2)])
#pragma unroll 1
    for (int w = 0; w < 7; ++w) {
        const int t = (w << 5) + L;
        if (t < TLEN) {
            const float4* xr4 = (const float4*)(xb + (size_t)t * ISZ);
            float a0c[12];
#pragma unroll
            for (int jj = 0; jj < 12; ++jj) a0c[jj] = 0.0f;
#pragma unroll
            for (int hh = 0; hh < 2; ++hh) {
                float4 xw[4];
#pragma unroll
                for (int q = 0; q < 4; ++q) xw[q] = xr4[(hh << 2) + q];
#pragma unroll
                for (int jh = 0; jh < 2; ++jh)
#pragma unroll
                    for (int kc = 0; kc < 4; ++kc)
#pragma unroll
                        for (int jj = jh * 6; jj < jh * 6 + 6; ++jj)
                            a0c[jj] += dot4(PLDSW(jj, (hh << 2) + kc), xw[kc]);
            }
            float vv[12];
#pragma unroll
            for (int jj = 0; jj < 12; ++jj) vv[jj] = a0c[jj] + lds[PBOFF + o * 12 + jj];
            // jj = gate*3 + v, unit = 3o+v  ->  float4 (i,f,g,o) per unit
            float4* dst = xp4 + ((size_t)b * TLEN + t) * 6 + 3 * o;
#pragma unroll
            for (int v = 0; v < 3; ++v)
                dst[v] = make_float4(vv[v], vv[3 + v], vv[6 + v], vv[9 + v]);
        }
    }
#undef PLDSW
}

// ======================= kernel 2: lane-per-unit scan =======================
__global__ __launch_bounds__(64) void lstm_scan(
    const float* __restrict__ Whh0, const float* __restrict__ Wih1,
    const float* __restrict__ Whh1, const float* __restrict__ Wlin,
    const float* __restrict__ blin, const float4* __restrict__ xp4,
    float* __restrict__ out)
{
    const int lane = threadIdx.x;
    const int role = lane & 15;
    const int grp  = lane >> 4;
    const int b    = blockIdx.x * 4 + grp;

    // per-lane weights: WA = Whh0 (L0) / Wih1 (L1); WB = 0 (L0) / Whh1 (L1)
    float WA[4][6], WB[4][6];
#pragma unroll
    for (int g = 0; g < 4; ++g)
#pragma unroll
        for (int k = 0; k < 6; ++k) { WA[g][k] = 0.0f; WB[g][k] = 0.0f; }
    if (role < 6) {
#pragma unroll
        for (int g = 0; g < 4; ++g)
#pragma unroll
            for (int k = 0; k < 6; ++k) WA[g][k] = Whh0[(g * 6 + role) * 6 + k];
    } else if (role < 12) {
        const int u = role - 6;
#pragma unroll
        for (int g = 0; g < 4; ++g)
#pragma unroll
            for (int k = 0; k < 6; ++k) {
                WA[g][k] = Wih1[(g * 6 + u) * 6 + k];
                WB[g][k] = Whh1[(g * 6 + u) * 6 + k];
            }
    }
    // xq stream: L0 lanes walk xp4[b][t][u] (stride 6 float4); L1/dummy lanes
    // pin a constant bias cell (stride 0) -> uniform step code, no selects.
    const float4* P;
    int ST;
    if (role < 6) { P = xp4 + (size_t)b * TLEN * 6 + role; ST = 6; }
    else          { P = xp4 + XP4_COUNT + (role < 12 ? role - 6 : 0); ST = 0; }

    float4 q0 = P[0], q1 = P[ST], q2 = P[2 * ST], q3 = P[3 * ST];
    P += 4 * ST;

    float c = 0.0f, h = 0.0f;

    // group-broadcast offsets: src_lane = (lane & 0x10) | k  ->  (k<<5)|0x10
#define STEP(XQ) do { \
    const float hA0 = swz<0x010>(h), hA1 = swz<0x030>(h), hA2 = swz<0x050>(h); \
    const float hA3 = swz<0x070>(h), hA4 = swz<0x090>(h), hA5 = swz<0x0B0>(h); \
    const float hB0 = swz<0x0D0>(h), hB1 = swz<0x0F0>(h), hB2 = swz<0x110>(h); \
    const float hB3 = swz<0x130>(h), hB4 = swz<0x150>(h), hB5 = swz<0x170>(h); \
    float a0 = (XQ).x, a1 = (XQ).y, a2 = (XQ).z, a3 = (XQ).w; \
    ARG(a0, 0); ARG(a1, 1); ARG(a2, 2); ARG(a3, 3); \
    const float ig = fast_sig(a0), fg = fast_sig(a1); \
    const float gg = tanh_s(a2),   og = fast_sig(a3); \
    c = fmaf(fg, c, ig * gg); \
    h = og * tanh_s(c); \
} while (0)

#define ARG(A, G) do { \
    const float s0 = fmaf(WA[G][0], hA0, fmaf(WA[G][1], hA1, fmaf(WA[G][2], hA2, A))); \
    const float s1 = fmaf(WA[G][3], hA3, fmaf(WA[G][4], hA4, WA[G][5] * hA5)); \
    const float s2 = fmaf(WB[G][0], hB0, fmaf(WB[G][1], hB1, WB[G][2] * hB2)); \
    const float s3 = fmaf(WB[G][3], hB3, fmaf(WB[G][4], hB4, WB[G][5] * hB5)); \
    A = (s0 + s1) + (s2 + s3); \
} while (0)

#define STEPR(QV) do { const float4 _xq = QV; QV = *P; P += ST; STEP(_xq); } while (0)

    // s = 0 peel: h=c=0 in; then erase L1/dummy phantom state (h1(-1) = 0)
    STEPR(q0);
    h = (role < 6) ? h : 0.0f;
    c = (role < 6) ? c : 0.0f;

    // s = 1..192 (48 x 4, rotating 4-deep prefetch; refill at s loads t=s+4)
#pragma unroll 1
    for (int m = 0; m < 48; ++m) {
        STEPR(q1); STEPR(q2); STEPR(q3); STEPR(q0);
    }
    // s = 193..195 (refill t=197..199), 196..199 (drain), 200 (phantom tail:
    // L0 consumes stale xp(196) -> finite, unused; L1 consumes bias -> t=199)
    STEPR(q1); STEPR(q2); STEPR(q3);
    STEP(q0); STEP(q1); STEP(q2); STEP(q3);
    STEP(q0);

    // head: h2_last lives on roles 6..11
    {
        const float f0 = swz<0x0D0>(h), f1 = swz<0x0F0>(h), f2 = swz<0x110>(h);
        const float f3 = swz<0x130>(h), f4 = swz<0x150>(h), f5 = swz<0x170>(h);
        float s = blin[0];
        s = fmaf(Wlin[0], f0, s); s = fmaf(Wlin[1], f1, s);
        s = fmaf(Wlin[2], f2, s); s = fmaf(Wlin[3], f3, s);
        s = fmaf(Wlin[4], f4, s); s = fmaf(Wlin[5], f5, s);
        if (role == 0) out[b] = s;
    }
#undef STEP
#undef ARG
#undef STEPR
}

// ======================= fallback: proven R8 kernel (135.5 us) =======================
__global__ __launch_bounds__(64) void lstm_fb(
    const float* __restrict__ x,
    const float* __restrict__ Wih0, const float* __restrict__ Whh0,
    const float* __restrict__ bih0, const float* __restrict__ bhh0,
    const float* __restrict__ Wih1, const float* __restrict__ Whh1,
    const float* __restrict__ bih1, const float* __restrict__ bhh1,
    const float* __restrict__ Wlin, const float* __restrict__ blin,
    float* __restrict__ out)
{
    __shared__ float lds[FLDS_DW];

    const int lane = threadIdx.x;
    const int b    = blockIdx.x;

    const int o = lane & 1;
    const int L = lane >> 1;

    const bool loHalf = (lane < 32);
    const int  p  = lane & 3;
    const int  jq = (lane & 31) >> 2;
    const int  j  = (jq < HSZ) ? jq : 0;
    const int  r  = 6 * p + j;

#define LDSW(ROW, KCQ) (*(const float4*)&lds[FWOFF + (o * 12 + (ROW)) * WPITCH + ((KCQ) << 2)])

#pragma unroll
    for (int k = 0; k < 13; ++k) {
        const int idx = lane + (k << 6);
        if (idx < 768) {
            const int row = idx >> 5, kk = idx & 31;
            lds[FWOFF + row * WPITCH + kk] = Wih0[idx];
        } else if (idx < 792) {
            lds[FBOFF + idx - 768] = bih0[idx - 768] + bhh0[idx - 768];
        }
    }

    float WA[6], WB[6], base1 = 0.0f, sgc = 1.0f, tgc = 0.0f;
#pragma unroll
    for (int k = 0; k < 6; ++k) { WA[k] = 0.0f; WB[k] = 0.0f; }
    if (loHalf) {
#pragma unroll
        for (int k = 0; k < 6; ++k) WA[k] = Whh0[r * 6 + k];
    } else {
#pragma unroll
        for (int k = 0; k < 6; ++k) { WA[k] = Wih1[r * 6 + k]; WB[k] = Whh1[r * 6 + k]; }
        base1 = bih1[r] + bhh1[r];
    }
    if (p == 2) {
#pragma unroll
        for (int k = 0; k < 6; ++k) { WA[k] *= 2.0f; WB[k] *= 2.0f; }
        base1 *= 2.0f; sgc = 2.0f; tgc = -1.0f;
    }

    const float* xb = x + (size_t)b * TLEN * ISZ;

#pragma unroll
    for (int w01 = 0; w01 < 2; ++w01) {
        const int t = (w01 << 5) + L;
        const float4* xr4 = (const float4*)(xb + t * ISZ);
        float4 xw[8];
#pragma unroll
        for (int q = 0; q < 8; ++q) xw[q] = xr4[q];
        float a0c[12];
#pragma unroll
        for (int jj = 0; jj < 12; ++jj) a0c[jj] = 0.0f;
#pragma unroll
        for (int kc = 0; kc < 8; ++kc)
#pragma unroll
            for (int jj = 0; jj < 12; ++jj)
                a0c[jj] += dot4(LDSW(jj, kc), xw[kc]);
#pragma unroll
        for (int jj = 0; jj < 12; ++jj) {
            float v = a0c[jj] + lds[FBOFF + o * 12 + jj];
            if (jj < 6) v = (o == 1) ? v * 2.0f : v;
            lds[t * RPITCH + o * 12 + jj] = v;
        }
    }

    float acc[12];
#pragma unroll
    for (int jj = 0; jj < 12; ++jj) acc[jj] = 0.0f;
    const float* pc = xb + (size_t)min(64 + L, TLEN - 1) * ISZ;
    const float* pn = xb + (size_t)min(96 + L, TLEN - 1) * ISZ;
    float4 f0, f1;
    f1 = *((const float4*)pc);
    float4 Wp0 = LDSW(0, 0), Wp1 = LDSW(1, 0), Wp2 = LDSW(2, 0);

    float c = 0.0f, h = 0.0f;
    float xp_cur = lds[r];

#define KC_HEAD(KC) do { \
    f0 = f1; \
    const float4* _srcp = ((KC) < 7) ? ((const float4*)pc + (KC) + 1) \
                                     : ((const float4*)pn); \
    f1 = *_srcp; \
} while (0)

#define SPREAD_STEP(RT, KC) do { \
    acc[3*(RT)+0] += dot4(Wp0, f0); \
    acc[3*(RT)+1] += dot4(Wp1, f0); \
    acc[3*(RT)+2] += dot4(Wp2, f0); \
    const int _rtn = ((RT) + 1) & 3; \
    const int _kcn = ((RT) == 3) ? (((KC) + 1) & 7) : (KC); \
    Wp0 = LDSW(3*_rtn + 0, _kcn); \
    Wp1 = LDSW(3*_rtn + 1, _kcn); \
    Wp2 = LDSW(3*_rtn + 2, _kcn); \
} while (0)

#define SCAN_STEP(ITV) do { \
    const float h10=rl(h,0),  h11=rl(h,4),  h12=rl(h,8); \
    const float h13=rl(h,12), h14=rl(h,16), h15=rl(h,20); \
    const float h20=rl(h,32), h21=rl(h,36), h22=rl(h,40); \
    const float h23=rl(h,44), h24=rl(h,48), h25=rl(h,52); \
    const float _xn = lds[(((ITV) + 1) & 63) * RPITCH + r]; \
    const float _g0 = loHalf ? xp_cur : base1; \
    const float _a0 = fmaf(WA[0],h10, fmaf(WA[2],h12, fmaf(WA[4],h14, _g0))); \
    const float _a1 = fmaf(WA[1],h11, fmaf(WA[3],h13, WA[5]*h15)); \
    const float _b0 = fmaf(WB[0],h20, fmaf(WB[2],h22, WB[4]*h24)); \
    const float _b1 = fmaf(WB[1],h21, fmaf(WB[3],h23, WB[5]*h25)); \
    const float _g  = (_a0 + _a1) + (_b0 + _b1); \
    const float _aG = fmaf(sgc, fast_sig(_g), tgc); \
    const float _iq = qperm<0x00>(_aG), _fq = qperm<0x55>(_aG); \
    const float _gq = qperm<0xAA>(_aG), _oq = qperm<0xFF>(_aG); \
    c = fmaf(_fq, c, _iq * _gq); \
    const float _th = fmaf(2.0f, fast_sig(2.0f * c), -1.0f); \
    h = _oq * _th; \
    xp_cur = _xn; \
    if ((ITV) == 200) { \
        float _s = blin[0]; \
        _s = fmaf(Wlin[0], rl(h, 32), _s); \
        _s = fmaf(Wlin[1], rl(h, 36), _s); \
        _s = fmaf(Wlin[2], rl(h, 40), _s); \
        _s = fmaf(Wlin[3], rl(h, 44), _s); \
        _s = fmaf(Wlin[4], rl(h, 48), _s); \
        _s = fmaf(Wlin[5], rl(h, 52), _s); \
        if (lane == 0) out[b] = _s; \
    } \
} while (0)

#define ENTRY(IT0) do { \
    const int _slot = ((IT0) + 32 + L) & 63; \
    _Pragma("unroll") \
    for (int _jj = 0; _jj < 12; ++_jj) { \
        float _v = acc[_jj] + lds[FBOFF + o * 12 + _jj]; \
        if (_jj < 6) _v = (o == 1) ? _v * 2.0f : _v; \
        lds[_slot * RPITCH + o * 12 + _jj] = _v; \
        acc[_jj] = 0.0f; \
    } \
    pc = pn; \
    pn = xb + (size_t)min((IT0) + 96 + L, TLEN - 1) * ISZ; \
} while (0)

    KC_HEAD(0);
    SPREAD_STEP(0, 0);
    {
        const float g  = loHalf ? xp_cur : base1;
        const float aG = fmaf(sgc, fast_sig(g), tgc);
        const float iq = qperm<0x00>(aG), gq = qperm<0xAA>(aG), oq = qperm<0xFF>(aG);
        const float cn = iq * gq;
        const float th = fmaf(2.0f, fast_sig(2.0f * cn), -1.0f);
        c = loHalf ? cn : 0.0f;
        h = loHalf ? (oq * th) : 0.0f;
        xp_cur = lds[RPITCH + r];
    }

    SPREAD_STEP(1, 0); SCAN_STEP(1);
    SPREAD_STEP(2, 0); SCAN_STEP(2);
    SPREAD_STEP(3, 0); SCAN_STEP(3);
    for (int kc = 1; kc < 8; ++kc) {
        KC_HEAD(kc);
        const int itb = kc << 2;
        SPREAD_STEP(0, kc); SCAN_STEP(itb + 0);
        SPREAD_STEP(1, kc); SCAN_STEP(itb + 1);
        SPREAD_STEP(2, kc); SCAN_STEP(itb + 2);
        SPREAD_STEP(3, kc); SCAN_STEP(itb + 3);
    }

    for (int w = 1; w < 7; ++w) {
        const int it0 = w << 5;
        ENTRY(it0);
        for (int kc = 0; kc < 8; ++kc) {
            const int itb = it0 + (kc << 2);
            if (itb > 200) break;
            KC_HEAD(kc);
            SPREAD_STEP(0, kc); SCAN_STEP(itb + 0);
            SPREAD_STEP(1, kc); SCAN_STEP(itb + 1);
            SPREAD_STEP(2, kc); SCAN_STEP(itb + 2);
            SPREAD_STEP(3, kc); SCAN_STEP(itb + 3);
        }
    }

#undef LDSW
#undef KC_HEAD
#undef SPREAD_STEP
#undef SCAN_STEP
#undef ENTRY
}

extern "C" void kernel_launch(void* const* d_in, const int* in_sizes, int n_in,
                              void* d_out, int out_size, void* d_ws, size_t ws_size,
                              hipStream_t stream) {
    const float* x    = (const float*)d_in[0];
    const float* Wih0 = (const float*)d_in[1];
    const float* Whh0 = (const float*)d_in[2];
    const float* bih0 = (const float*)d_in[3];
    const float* bhh0 = (const float*)d_in[4];
    const float* Wih1 = (const float*)d_in[5];
    const float* Whh1 = (const float*)d_in[6];
    const float* bih1 = (const float*)d_in[7];
    const float* bhh1 = (const float*)d_in[8];
    const float* Wlin = (const float*)d_in[9];
    const float* blin = (const float*)d_in[10];
    float* out = (float*)d_out;

    if (d_ws != nullptr && ws_size >= WS_REQ) {
        float4* xp4 = (float4*)d_ws;
        proj_k<<<4096, 64, 0, stream>>>(x, Wih0, bih0, bhh0, bih1, bhh1, xp4);
        lstm_scan<<<1024, 64, 0, stream>>>(Whh0, Wih1, Whh1, Wlin, blin,
                                           (const float4*)xp4, out);
    } else {
        lstm_fb<<<4096, 64, 0, stream>>>(x, Wih0, Whh0, bih0, bhh0,
                                         Wih1, Whh1, bih1, bhh1,
                                         Wlin, blin, out);
    }
}